// Round 4
// baseline (42.113 us; speedup 1.0000x reference)
//
#include <hip/hip_runtime.h>
#include <stdint.h>

// ---------------------------------------------------------------------------
// SpecAugment: out[b,d,t] = x[b,d,t] * keep[b,d,t]
// keep derived from jax.random.key(42) via threefry2x32 — replicated bit-exact
// (partitionable mode, verified absmax=0 in R1/R3).
// R4: 8-deep batched loads (2 groups), fmask==0 branch-free fast path,
// SGPR row bases, nt stores, 2-way (was 4-way) setup divergence.
// ---------------------------------------------------------------------------
#define BB 64
#define DD 128
#define NT4 1000   // T/4 = 4000/4

typedef float f32x4 __attribute__((ext_vector_type(4)));

__device__ __forceinline__ uint32_t rotl32(uint32_t v, int r) {
  return (v << r) | (v >> (32 - r));
}

// Standard Threefry-2x32, 20 rounds, as in jax/_src/prng.py
__device__ __forceinline__ void threefry2x32(uint32_t k0, uint32_t k1,
                                             uint32_t x0, uint32_t x1,
                                             uint32_t& o0, uint32_t& o1) {
  const uint32_t ks2 = k0 ^ k1 ^ 0x1BD11BDAu;
  x0 += k0; x1 += k1;
#define TF_R(r) { x0 += x1; x1 = rotl32(x1, r); x1 ^= x0; }
  TF_R(13) TF_R(15) TF_R(26) TF_R(6)
  x0 += k1;  x1 += ks2 + 1u;
  TF_R(17) TF_R(29) TF_R(16) TF_R(24)
  x0 += ks2; x1 += k0 + 2u;
  TF_R(13) TF_R(15) TF_R(26) TF_R(6)
  x0 += k0;  x1 += k1 + 3u;
  TF_R(17) TF_R(29) TF_R(16) TF_R(24)
  x0 += k1;  x1 += ks2 + 4u;
  TF_R(13) TF_R(15) TF_R(26) TF_R(6)
  x0 += ks2; x1 += k0 + 5u;
#undef TF_R
  o0 = x0; o1 = x1;
}

// random_bits(key, 32, shape)[j] — partitionable mode
__device__ __forceinline__ uint32_t jax_bits32(uint32_t ka, uint32_t kb, uint32_t j) {
  uint32_t a, b;
  threefry2x32(ka, kb, 0u, j, a, b);   // counter = uint64 j -> (hi=0, lo=j)
  return a ^ b;                        // 32-bit width: xor of both halves
}

// i-th key of jax.random.split(key(42), 4) — fold-like split
__device__ __forceinline__ void jax_subkey42(int i, uint32_t& oa, uint32_t& ob) {
  threefry2x32(0u, 42u, 0u, (uint32_t)i, oa, ob);
}

// jax.random.randint(key, shape, 0, span)[flat j]; mult = 2^32 % span
__device__ __forceinline__ uint32_t jax_randint0(uint32_t ka, uint32_t kb, uint32_t j,
                                                 uint32_t span, uint32_t mult) {
  uint32_t k1a, k1b, k2a, k2b;
  threefry2x32(ka, kb, 0u, 0u, k1a, k1b);   // _split(key)[0]
  threefry2x32(ka, kb, 0u, 1u, k2a, k2b);   // _split(key)[1]
  uint32_t hb = jax_bits32(k1a, k1b, j);
  uint32_t lb = jax_bits32(k2a, k2b, j);
  // ((hi % s) * (2^32 % s) + (lo % s)) % s  — no uint32 overflow for span<=102
  return ((hb % span) * mult + (lb % span)) % span;
}

__global__ __launch_bounds__(256, 8) void specaug_kernel(
    const float* __restrict__ x, const int* __restrict__ len,
    float* __restrict__ out) {
  // s_par layout: [0:2) f_start, [2:4) f_w, [4:14) t_start, [14:24) t_w
  __shared__ int s_par[24];
  const int b   = blockIdx.y;
  const int tid = threadIdx.x;

  if (tid < 24) {
    if (tid < 4 || tid >= 14) {          // randint lanes: fs, fw, tw
      const int      keyi = tid < 2 ? 0 : (tid < 4 ? 1 : 3);
      const uint32_t span = tid < 2 ? 102u : (tid < 4 ? 28u : 101u);
      const uint32_t mult = tid < 2 ? 52u  : (tid < 4 ? 4u  : 68u);
      const uint32_t j    = tid < 4 ? (uint32_t)(b * 2 + (tid & 1))
                                    : (uint32_t)(b * 10 + tid - 14);
      uint32_t ka, kb; jax_subkey42(keyi, ka, kb);
      s_par[tid] = (int)jax_randint0(ka, kb, j, span, mult);
    } else {                             // t_start lanes: floor(uniform * max_start)
      const int m = tid - 4;
      uint32_t ka, kb; jax_subkey42(2, ka, kb);
      uint32_t bits = jax_bits32(ka, kb, (uint32_t)(b * 10 + m));
      float u = __uint_as_float((bits >> 9) | 0x3F800000u) - 1.0f;  // [0,1)
      int ms = len[b] - 99; if (ms < 1) ms = 1;                     // max(len-TW+1, 1)
      s_par[tid] = (int)floorf(u * (float)ms);
    }
  }
  __syncthreads();

  const int t4 = blockIdx.x * 256 + tid;   // float4 index within row
  if (t4 >= NT4) return;                   // no further barriers -> safe early-exit
  const int t0 = t4 * 4;

  // per-component time-keep multiplier (0.0 where any time mask hits)
  float m0 = 1.f, m1 = 1.f, m2 = 1.f, m3 = 1.f;
#pragma unroll
  for (int m = 0; m < 10; ++m) {
    int ts = s_par[4 + m], te = ts + s_par[14 + m];
    if (t0     >= ts && t0     < te) m0 = 0.f;
    if (t0 + 1 >= ts && t0 + 1 < te) m1 = 0.f;
    if (t0 + 2 >= ts && t0 + 2 < te) m2 = 0.f;
    if (t0 + 3 >= ts && t0 + 3 < te) m3 = 0.f;
  }
  const f32x4 mm = (f32x4){m0, m1, m2, m3};

  const int d0 = blockIdx.z * 16;
  // freq-hit bitmask for this block's 16 d-rows (block-uniform) -> SGPR
  const int fs0 = s_par[0], fe0 = fs0 + s_par[2];
  const int fs1 = s_par[1], fe1 = fs1 + s_par[3];
  uint32_t fmask = 0;
#pragma unroll
  for (int u = 0; u < 16; ++u) {
    int d = d0 + u;
    bool fh = (d >= fs0 && d < fe0) || (d >= fs1 && d < fe1);
    fmask |= (uint32_t)fh << u;
  }
  fmask = (uint32_t)__builtin_amdgcn_readfirstlane((int)fmask);  // scalar branches

  const f32x4* __restrict__ x4 = reinterpret_cast<const f32x4*>(x);
  f32x4* __restrict__ o4       = reinterpret_cast<f32x4*>(out);
  const size_t rowbase = (size_t)(b * DD + d0) * NT4;  // block-uniform -> SGPR bases

  if (fmask == 0u) {
    // fast path (~56% of blocks): branch-free, 8 clustered loads per group
#pragma unroll
    for (int g = 0; g < 2; ++g) {
      f32x4 v[8];
#pragma unroll
      for (int r = 0; r < 8; ++r)
        v[r] = x4[rowbase + (size_t)(g * 8 + r) * NT4 + t4];
#pragma unroll
      for (int r = 0; r < 8; ++r) {
        v[r] *= mm;
        __builtin_nontemporal_store(v[r], &o4[rowbase + (size_t)(g * 8 + r) * NT4 + t4]);
      }
    }
  } else {
    const f32x4 z4 = (f32x4){0.f, 0.f, 0.f, 0.f};
#pragma unroll
    for (int g = 0; g < 2; ++g) {
      const uint32_t fm = (fmask >> (g * 8)) & 0xFFu;  // scalar
      f32x4 v[8];
#pragma unroll
      for (int r = 0; r < 8; ++r) {
        v[r] = z4;
        if (!((fm >> r) & 1u))                          // uniform scalar branch
          v[r] = x4[rowbase + (size_t)(g * 8 + r) * NT4 + t4];
      }
#pragma unroll
      for (int r = 0; r < 8; ++r) {
        v[r] *= mm;
        __builtin_nontemporal_store(v[r], &o4[rowbase + (size_t)(g * 8 + r) * NT4 + t4]);
      }
    }
  }
}

extern "C" void kernel_launch(void* const* d_in, const int* in_sizes, int n_in,
                              void* d_out, int out_size, void* d_ws, size_t ws_size,
                              hipStream_t stream) {
  (void)in_sizes; (void)n_in; (void)d_ws; (void)ws_size; (void)out_size;
  const float* x  = (const float*)d_in[0];
  const int* len  = (const int*)d_in[1];
  float* out      = (float*)d_out;
  dim3 grid(4 /* ceil(NT4/256) */, BB, DD / 16);
  dim3 block(256);
  hipLaunchKernelGGL(specaug_kernel, grid, block, 0, stream, x, len, out);
}

// Round 6
// 41.346 us; speedup vs baseline: 1.0185x; 1.0185x over previous
//
#include <hip/hip_runtime.h>
#include <stdint.h>

// ---------------------------------------------------------------------------
// SpecAugment: out[b,d,t] = x[b,d,t] * keep[b,d,t]
// keep derived from jax.random.key(42) via threefry2x32 — replicated bit-exact
// (partitionable mode, verified absmax=0 in R1/R3/R4).
// R6: retry sc1+nt store experiment with a HAZARD-SAFE structure — all 16
// stores in ONE asm block at kernel end (R5's per-store asm let the compiler
// reuse in-flight store-data VGPRs -> corruption). Address stepped inside the
// asm via v_lshl_add_u64 (stride in SGPR pair; VOP3 takes no literal).
// ---------------------------------------------------------------------------
#define BB 64
#define DD 128
#define NT4 1000   // T/4 = 4000/4

typedef float f32x4 __attribute__((ext_vector_type(4)));

__device__ __forceinline__ uint32_t rotl32(uint32_t v, int r) {
  return (v << r) | (v >> (32 - r));
}

// Standard Threefry-2x32, 20 rounds, as in jax/_src/prng.py
__device__ __forceinline__ void threefry2x32(uint32_t k0, uint32_t k1,
                                             uint32_t x0, uint32_t x1,
                                             uint32_t& o0, uint32_t& o1) {
  const uint32_t ks2 = k0 ^ k1 ^ 0x1BD11BDAu;
  x0 += k0; x1 += k1;
#define TF_R(r) { x0 += x1; x1 = rotl32(x1, r); x1 ^= x0; }
  TF_R(13) TF_R(15) TF_R(26) TF_R(6)
  x0 += k1;  x1 += ks2 + 1u;
  TF_R(17) TF_R(29) TF_R(16) TF_R(24)
  x0 += ks2; x1 += k0 + 2u;
  TF_R(13) TF_R(15) TF_R(26) TF_R(6)
  x0 += k0;  x1 += k1 + 3u;
  TF_R(17) TF_R(29) TF_R(16) TF_R(24)
  x0 += k1;  x1 += ks2 + 4u;
  TF_R(13) TF_R(15) TF_R(26) TF_R(6)
  x0 += ks2; x1 += k0 + 5u;
#undef TF_R
  o0 = x0; o1 = x1;
}

// random_bits(key, 32, shape)[j] — partitionable mode
__device__ __forceinline__ uint32_t jax_bits32(uint32_t ka, uint32_t kb, uint32_t j) {
  uint32_t a, b;
  threefry2x32(ka, kb, 0u, j, a, b);   // counter = uint64 j -> (hi=0, lo=j)
  return a ^ b;                        // 32-bit width: xor of both halves
}

// i-th key of jax.random.split(key(42), 4) — fold-like split
__device__ __forceinline__ void jax_subkey42(int i, uint32_t& oa, uint32_t& ob) {
  threefry2x32(0u, 42u, 0u, (uint32_t)i, oa, ob);
}

// jax.random.randint(key, shape, 0, span)[flat j]; mult = 2^32 % span
__device__ __forceinline__ uint32_t jax_randint0(uint32_t ka, uint32_t kb, uint32_t j,
                                                 uint32_t span, uint32_t mult) {
  uint32_t k1a, k1b, k2a, k2b;
  threefry2x32(ka, kb, 0u, 0u, k1a, k1b);   // _split(key)[0]
  threefry2x32(ka, kb, 0u, 1u, k2a, k2b);   // _split(key)[1]
  uint32_t hb = jax_bits32(k1a, k1b, j);
  uint32_t lb = jax_bits32(k2a, k2b, j);
  // ((hi % s) * (2^32 % s) + (lo % s)) % s  — no uint32 overflow for span<=102
  return ((hb % span) * mult + (lb % span)) % span;
}

__global__ __launch_bounds__(256, 4) void specaug_kernel(
    const float* __restrict__ x, const int* __restrict__ len,
    float* __restrict__ out) {
  // s_par layout: [0:2) f_start, [2:4) f_w, [4:14) t_start, [14:24) t_w
  __shared__ int s_par[24];
  const int b   = blockIdx.y;
  const int tid = threadIdx.x;

  if (tid < 24) {
    if (tid < 4 || tid >= 14) {          // randint lanes: fs, fw, tw
      const int      keyi = tid < 2 ? 0 : (tid < 4 ? 1 : 3);
      const uint32_t span = tid < 2 ? 102u : (tid < 4 ? 28u : 101u);
      const uint32_t mult = tid < 2 ? 52u  : (tid < 4 ? 4u  : 68u);
      const uint32_t j    = tid < 4 ? (uint32_t)(b * 2 + (tid & 1))
                                    : (uint32_t)(b * 10 + tid - 14);
      uint32_t ka, kb; jax_subkey42(keyi, ka, kb);
      s_par[tid] = (int)jax_randint0(ka, kb, j, span, mult);
    } else {                             // t_start lanes: floor(uniform * max_start)
      const int m = tid - 4;
      uint32_t ka, kb; jax_subkey42(2, ka, kb);
      uint32_t bits = jax_bits32(ka, kb, (uint32_t)(b * 10 + m));
      float u = __uint_as_float((bits >> 9) | 0x3F800000u) - 1.0f;  // [0,1)
      int ms = len[b] - 99; if (ms < 1) ms = 1;                     // max(len-TW+1, 1)
      s_par[tid] = (int)floorf(u * (float)ms);
    }
  }
  __syncthreads();

  const int t4 = blockIdx.x * 256 + tid;   // float4 index within row
  if (t4 >= NT4) return;                   // no further barriers -> safe early-exit
  const int t0 = t4 * 4;

  // per-component time-keep multiplier (0.0 where any time mask hits)
  float m0 = 1.f, m1 = 1.f, m2 = 1.f, m3 = 1.f;
#pragma unroll
  for (int m = 0; m < 10; ++m) {
    int ts = s_par[4 + m], te = ts + s_par[14 + m];
    if (t0     >= ts && t0     < te) m0 = 0.f;
    if (t0 + 1 >= ts && t0 + 1 < te) m1 = 0.f;
    if (t0 + 2 >= ts && t0 + 2 < te) m2 = 0.f;
    if (t0 + 3 >= ts && t0 + 3 < te) m3 = 0.f;
  }
  const f32x4 mm = (f32x4){m0, m1, m2, m3};

  const int d0 = blockIdx.z * 16;
  // freq-hit bitmask for this block's 16 d-rows (block-uniform) -> SGPR
  const int fs0 = s_par[0], fe0 = fs0 + s_par[2];
  const int fs1 = s_par[1], fe1 = fs1 + s_par[3];
  uint32_t fmask = 0;
#pragma unroll
  for (int u = 0; u < 16; ++u) {
    int d = d0 + u;
    bool fh = (d >= fs0 && d < fe0) || (d >= fs1 && d < fe1);
    fmask |= (uint32_t)fh << u;
  }
  fmask = (uint32_t)__builtin_amdgcn_readfirstlane((int)fmask);  // scalar branches

  const f32x4* __restrict__ x4 = reinterpret_cast<const f32x4*>(x);
  const size_t rowbase = (size_t)(b * DD + d0) * NT4;  // block-uniform -> SGPR bases
  const f32x4 z4 = (f32x4){0.f, 0.f, 0.f, 0.f};

  // ---- load phase: all 16 rows into registers ----
  f32x4 v[16];
  if (fmask == 0u) {
#pragma unroll
    for (int r = 0; r < 16; ++r)
      v[r] = x4[rowbase + (size_t)r * NT4 + t4];
  } else {
#pragma unroll
    for (int r = 0; r < 16; ++r) {
      v[r] = z4;
      if (!((fmask >> r) & 1u))                         // uniform scalar branch
        v[r] = x4[rowbase + (size_t)r * NT4 + t4];
    }
  }
#pragma unroll
  for (int r = 0; r < 16; ++r) v[r] *= mm;

  // ---- store phase: ONE asm block, nothing after it (no reg-reuse hazard).
  // addr steps by row stride (NT4*16 B) via v_lshl_add_u64 (stride in SGPR).
  uint64_t addr = (uint64_t)(uintptr_t)out + ((rowbase + (size_t)t4) << 4);
  const uint64_t stride = (uint64_t)NT4 * 16u;
#define ST(i) "global_store_dwordx4 %[a], %[d" #i "], off sc1 nt\n\t" \
              "v_lshl_add_u64 %[a], %[s], 0, %[a]\n\t"
  asm volatile(
      ST(0) ST(1) ST(2) ST(3) ST(4) ST(5) ST(6) ST(7)
      ST(8) ST(9) ST(10) ST(11) ST(12) ST(13) ST(14)
      "global_store_dwordx4 %[a], %[d15], off sc1 nt"
      : [a] "+v"(addr)
      : [s] "s"(stride),
        [d0] "v"(v[0]),  [d1] "v"(v[1]),  [d2] "v"(v[2]),  [d3] "v"(v[3]),
        [d4] "v"(v[4]),  [d5] "v"(v[5]),  [d6] "v"(v[6]),  [d7] "v"(v[7]),
        [d8] "v"(v[8]),  [d9] "v"(v[9]),  [d10] "v"(v[10]), [d11] "v"(v[11]),
        [d12] "v"(v[12]), [d13] "v"(v[13]), [d14] "v"(v[14]), [d15] "v"(v[15])
      : "memory");
#undef ST
}

extern "C" void kernel_launch(void* const* d_in, const int* in_sizes, int n_in,
                              void* d_out, int out_size, void* d_ws, size_t ws_size,
                              hipStream_t stream) {
  (void)in_sizes; (void)n_in; (void)d_ws; (void)ws_size; (void)out_size;
  const float* x  = (const float*)d_in[0];
  const int* len  = (const int*)d_in[1];
  float* out      = (float*)d_out;
  dim3 grid(4 /* ceil(NT4/256) */, BB, DD / 16);
  dim3 block(256);
  hipLaunchKernelGGL(specaug_kernel, grid, block, 0, stream, x, len, out);
}

// Round 7
// 40.309 us; speedup vs baseline: 1.0447x; 1.0257x over previous
//
#include <hip/hip_runtime.h>
#include <stdint.h>

// ---------------------------------------------------------------------------
// SpecAugment: out[b,d,t] = x[b,d,t] * keep[b,d,t]
// keep derived from jax.random.key(42) via threefry2x32 — replicated bit-exact
// (partitionable mode, verified absmax=0 in R1/R3/R4/R6).
// R7: R6 + time-mask read skip — lanes whose 4 t-cols are all time-masked
// skip the entire 16-row load cluster (one saveexec region; ~100-wide mask
// runs cover whole 64B lines -> real FETCH reduction). Stores unchanged
// (single hazard-safe asm block; sc1 nt proven neutral but harmless).
// ---------------------------------------------------------------------------
#define BB 64
#define DD 128
#define NT4 1000   // T/4 = 4000/4

typedef float f32x4 __attribute__((ext_vector_type(4)));

__device__ __forceinline__ uint32_t rotl32(uint32_t v, int r) {
  return (v << r) | (v >> (32 - r));
}

// Standard Threefry-2x32, 20 rounds, as in jax/_src/prng.py
__device__ __forceinline__ void threefry2x32(uint32_t k0, uint32_t k1,
                                             uint32_t x0, uint32_t x1,
                                             uint32_t& o0, uint32_t& o1) {
  const uint32_t ks2 = k0 ^ k1 ^ 0x1BD11BDAu;
  x0 += k0; x1 += k1;
#define TF_R(r) { x0 += x1; x1 = rotl32(x1, r); x1 ^= x0; }
  TF_R(13) TF_R(15) TF_R(26) TF_R(6)
  x0 += k1;  x1 += ks2 + 1u;
  TF_R(17) TF_R(29) TF_R(16) TF_R(24)
  x0 += ks2; x1 += k0 + 2u;
  TF_R(13) TF_R(15) TF_R(26) TF_R(6)
  x0 += k0;  x1 += k1 + 3u;
  TF_R(17) TF_R(29) TF_R(16) TF_R(24)
  x0 += k1;  x1 += ks2 + 4u;
  TF_R(13) TF_R(15) TF_R(26) TF_R(6)
  x0 += ks2; x1 += k0 + 5u;
#undef TF_R
  o0 = x0; o1 = x1;
}

// random_bits(key, 32, shape)[j] — partitionable mode
__device__ __forceinline__ uint32_t jax_bits32(uint32_t ka, uint32_t kb, uint32_t j) {
  uint32_t a, b;
  threefry2x32(ka, kb, 0u, j, a, b);   // counter = uint64 j -> (hi=0, lo=j)
  return a ^ b;                        // 32-bit width: xor of both halves
}

// i-th key of jax.random.split(key(42), 4) — fold-like split
__device__ __forceinline__ void jax_subkey42(int i, uint32_t& oa, uint32_t& ob) {
  threefry2x32(0u, 42u, 0u, (uint32_t)i, oa, ob);
}

// jax.random.randint(key, shape, 0, span)[flat j]; mult = 2^32 % span
__device__ __forceinline__ uint32_t jax_randint0(uint32_t ka, uint32_t kb, uint32_t j,
                                                 uint32_t span, uint32_t mult) {
  uint32_t k1a, k1b, k2a, k2b;
  threefry2x32(ka, kb, 0u, 0u, k1a, k1b);   // _split(key)[0]
  threefry2x32(ka, kb, 0u, 1u, k2a, k2b);   // _split(key)[1]
  uint32_t hb = jax_bits32(k1a, k1b, j);
  uint32_t lb = jax_bits32(k2a, k2b, j);
  // ((hi % s) * (2^32 % s) + (lo % s)) % s  — no uint32 overflow for span<=102
  return ((hb % span) * mult + (lb % span)) % span;
}

__global__ __launch_bounds__(256, 4) void specaug_kernel(
    const float* __restrict__ x, const int* __restrict__ len,
    float* __restrict__ out) {
  // s_par layout: [0:2) f_start, [2:4) f_w, [4:14) t_start, [14:24) t_w
  __shared__ int s_par[24];
  const int b   = blockIdx.y;
  const int tid = threadIdx.x;

  if (tid < 24) {
    if (tid < 4 || tid >= 14) {          // randint lanes: fs, fw, tw
      const int      keyi = tid < 2 ? 0 : (tid < 4 ? 1 : 3);
      const uint32_t span = tid < 2 ? 102u : (tid < 4 ? 28u : 101u);
      const uint32_t mult = tid < 2 ? 52u  : (tid < 4 ? 4u  : 68u);
      const uint32_t j    = tid < 4 ? (uint32_t)(b * 2 + (tid & 1))
                                    : (uint32_t)(b * 10 + tid - 14);
      uint32_t ka, kb; jax_subkey42(keyi, ka, kb);
      s_par[tid] = (int)jax_randint0(ka, kb, j, span, mult);
    } else {                             // t_start lanes: floor(uniform * max_start)
      const int m = tid - 4;
      uint32_t ka, kb; jax_subkey42(2, ka, kb);
      uint32_t bits = jax_bits32(ka, kb, (uint32_t)(b * 10 + m));
      float u = __uint_as_float((bits >> 9) | 0x3F800000u) - 1.0f;  // [0,1)
      int ms = len[b] - 99; if (ms < 1) ms = 1;                     // max(len-TW+1, 1)
      s_par[tid] = (int)floorf(u * (float)ms);
    }
  }
  __syncthreads();

  const int t4 = blockIdx.x * 256 + tid;   // float4 index within row
  if (t4 >= NT4) return;                   // no further barriers -> safe early-exit
  const int t0 = t4 * 4;

  // per-component time-keep multiplier (0.0 where any time mask hits)
  float m0 = 1.f, m1 = 1.f, m2 = 1.f, m3 = 1.f;
#pragma unroll
  for (int m = 0; m < 10; ++m) {
    int ts = s_par[4 + m], te = ts + s_par[14 + m];
    if (t0     >= ts && t0     < te) m0 = 0.f;
    if (t0 + 1 >= ts && t0 + 1 < te) m1 = 0.f;
    if (t0 + 2 >= ts && t0 + 2 < te) m2 = 0.f;
    if (t0 + 3 >= ts && t0 + 3 < te) m3 = 0.f;
  }
  const f32x4 mm = (f32x4){m0, m1, m2, m3};
  const bool tz = (m0 + m1 + m2 + m3) == 0.f;   // all 4 t-cols time-masked

  const int d0 = blockIdx.z * 16;
  // freq-hit bitmask for this block's 16 d-rows (block-uniform) -> SGPR
  const int fs0 = s_par[0], fe0 = fs0 + s_par[2];
  const int fs1 = s_par[1], fe1 = fs1 + s_par[3];
  uint32_t fmask = 0;
#pragma unroll
  for (int u = 0; u < 16; ++u) {
    int d = d0 + u;
    bool fh = (d >= fs0 && d < fe0) || (d >= fs1 && d < fe1);
    fmask |= (uint32_t)fh << u;
  }
  fmask = (uint32_t)__builtin_amdgcn_readfirstlane((int)fmask);  // scalar branches

  const f32x4* __restrict__ x4 = reinterpret_cast<const f32x4*>(x);
  const size_t rowbase = (size_t)(b * DD + d0) * NT4;  // block-uniform -> SGPR bases
  const f32x4 z4 = (f32x4){0.f, 0.f, 0.f, 0.f};

  // ---- load phase: all 16 rows into registers; tz lanes skip every load
  // (one divergent region -> one saveexec; masked lanes issue no mem requests,
  //  and ~100-wide mask runs cover whole 64B lines -> fewer line fetches) ----
  f32x4 v[16];
#pragma unroll
  for (int r = 0; r < 16; ++r) v[r] = z4;
  if (!tz) {
    if (fmask == 0u) {
#pragma unroll
      for (int r = 0; r < 16; ++r)
        v[r] = x4[rowbase + (size_t)r * NT4 + t4];
    } else {
#pragma unroll
      for (int r = 0; r < 16; ++r) {
        if (!((fmask >> r) & 1u))                       // uniform scalar branch
          v[r] = x4[rowbase + (size_t)r * NT4 + t4];
      }
    }
  }
#pragma unroll
  for (int r = 0; r < 16; ++r) v[r] *= mm;

  // ---- store phase: ONE asm block, nothing after it (no reg-reuse hazard).
  // addr steps by row stride (NT4*16 B) via v_lshl_add_u64 (stride in SGPR).
  uint64_t addr = (uint64_t)(uintptr_t)out + ((rowbase + (size_t)t4) << 4);
  const uint64_t stride = (uint64_t)NT4 * 16u;
#define ST(i) "global_store_dwordx4 %[a], %[d" #i "], off sc1 nt\n\t" \
              "v_lshl_add_u64 %[a], %[s], 0, %[a]\n\t"
  asm volatile(
      ST(0) ST(1) ST(2) ST(3) ST(4) ST(5) ST(6) ST(7)
      ST(8) ST(9) ST(10) ST(11) ST(12) ST(13) ST(14)
      "global_store_dwordx4 %[a], %[d15], off sc1 nt"
      : [a] "+v"(addr)
      : [s] "s"(stride),
        [d0] "v"(v[0]),  [d1] "v"(v[1]),  [d2] "v"(v[2]),  [d3] "v"(v[3]),
        [d4] "v"(v[4]),  [d5] "v"(v[5]),  [d6] "v"(v[6]),  [d7] "v"(v[7]),
        [d8] "v"(v[8]),  [d9] "v"(v[9]),  [d10] "v"(v[10]), [d11] "v"(v[11]),
        [d12] "v"(v[12]), [d13] "v"(v[13]), [d14] "v"(v[14]), [d15] "v"(v[15])
      : "memory");
#undef ST
}

extern "C" void kernel_launch(void* const* d_in, const int* in_sizes, int n_in,
                              void* d_out, int out_size, void* d_ws, size_t ws_size,
                              hipStream_t stream) {
  (void)in_sizes; (void)n_in; (void)d_ws; (void)ws_size; (void)out_size;
  const float* x  = (const float*)d_in[0];
  const int* len  = (const int*)d_in[1];
  float* out      = (float*)d_out;
  dim3 grid(4 /* ceil(NT4/256) */, BB, DD / 16);
  dim3 block(256);
  hipLaunchKernelGGL(specaug_kernel, grid, block, 0, stream, x, len, out);
}